// Round 1
// baseline (387.231 us; speedup 1.0000x reference)
//
#include <hip/hip_runtime.h>
#include <hip/hip_bf16.h>
#include <stdint.h>

typedef __attribute__((ext_vector_type(8))) short s8v;   // 8 bf16 (4 VGPRs) MFMA A/B frag
typedef __attribute__((ext_vector_type(4))) float f4v;   // MFMA C/D frag
typedef __attribute__((ext_vector_type(4))) int i4v;     // 16B staging

#define NE   128
#define NT   2048
#define DIN  128
#define DH   512
#define DOUT 128

__device__ __forceinline__ ushort f2bf(float f) {
  uint32_t u = __float_as_uint(f);
  u += 0x7FFFu + ((u >> 16) & 1u);   // RTNE
  return (ushort)(u >> 16);
}

__device__ __forceinline__ float gelu_f(float x) {
  // tanh-form GELU; |err vs exact erf| < ~1e-3, threshold is 1.04e-1
  float t = 0.7978845608028654f * x * (1.0f + 0.044715f * x * x);
  float e = __expf(2.0f * t);
  float th = (e - 1.0f) / (e + 1.0f);
  return 0.5f * x * (1.0f + th);
}

// src [e][R][C] fp32 -> dst [e][C][R] bf16 (64x64 LDS-tiled transpose)
__global__ __launch_bounds__(256) void transpose_cvt(
    const float* __restrict__ src, ushort* __restrict__ dst, int R, int C) {
  const int tilesR = R >> 6, tilesC = C >> 6;
  const int bid = blockIdx.x;
  const int e   = bid / (tilesR * tilesC);
  const int rem = bid % (tilesR * tilesC);
  const int tr = rem / tilesC, tc = rem % tilesC;
  const float* S = src + (size_t)e * R * C + (size_t)(tr << 6) * C + (tc << 6);
  ushort*      D = dst + (size_t)e * R * C + (size_t)(tc << 6) * R + (tr << 6);
  __shared__ float tile[64][65];
  const int tid = threadIdx.x;
#pragma unroll
  for (int it = 0; it < 4; ++it) {
    int s = (it << 8) + tid;                 // 1024 slots
    int r = s >> 4, cg = (s & 15) << 2;
    float4 v = *(const float4*)(S + (size_t)r * C + cg);
    tile[r][cg + 0] = v.x; tile[r][cg + 1] = v.y;
    tile[r][cg + 2] = v.z; tile[r][cg + 3] = v.w;
  }
  __syncthreads();
#pragma unroll
  for (int it = 0; it < 4; ++it) {
    int s = (it << 8) + tid;
    int c = s >> 4, rg = (s & 15) << 2;
    ushort4 w;
    w.x = f2bf(tile[rg + 0][c]); w.y = f2bf(tile[rg + 1][c]);
    w.z = f2bf(tile[rg + 2][c]); w.w = f2bf(tile[rg + 3][c]);
    *(ushort4*)(D + (size_t)c * R + rg) = w;
  }
}

// Fused per-expert: out = gelu(X @ W1) @ W2.
// Block: 128 tokens. Hidden looped in 16 chunks of 32.
// Stage1 computes H^T (A=W1t rows h, B=X^T cols m) so D-regs (4 consecutive h,
// fixed m) pack into one b64 write to Hs[m][h] == stage2's A-operand layout.
__global__ __launch_bounds__(256, 2) void moe_fused(
    const float* __restrict__ X, const ushort* __restrict__ W1t,
    const ushort* __restrict__ W2t, float* __restrict__ Out) {
  // all rows are 16B-chunk XOR-swizzled to kill bank conflicts (rows are
  // bank-aligned power-of-2 strides; swizzle keeps reads/writes <=2-way = free)
  __shared__ ushort Xs[128 * 128];   // [m][d]      row 256B, 16 chunks
  __shared__ ushort W1s[32 * 128];   // [h_loc][d]  row 256B, 16 chunks
  __shared__ ushort W2s[128 * 32];   // [o][h_loc]  row  64B,  4 chunks
  __shared__ ushort Hs[128 * 32];    // [m][h_loc]  row  64B,  4 chunks

  const int tid  = threadIdx.x;
  const int lane = tid & 63;
  const int wid  = tid >> 6;
  const int quad = lane >> 4;
  const int l16  = lane & 15;

  const int e    = blockIdx.x >> 4;
  const int tile = blockIdx.x & 15;

  const float*  Xe  = X   + ((size_t)e * NT + (size_t)tile * 128) * DIN;
  const ushort* W1e = W1t + (size_t)e * DH * DIN;   // [h][d]
  const ushort* W2e = W2t + (size_t)e * DOUT * DH;  // [o][h]
  float*        Oe  = Out + ((size_t)e * NT + (size_t)tile * 128) * DOUT;

  // ---- stage X -> Xs (fp32 -> bf16, swizzled) ----
#pragma unroll
  for (int it = 0; it < 8; ++it) {
    int s = (it << 8) + tid;              // 2048 slots of 8 elems
    int m = s >> 4, c = s & 15;
    const float* p = Xe + m * DIN + (c << 3);
    float4 v0 = *(const float4*)p;
    float4 v1 = *(const float4*)(p + 4);
    s8v w;
    w[0] = (short)f2bf(v0.x); w[1] = (short)f2bf(v0.y);
    w[2] = (short)f2bf(v0.z); w[3] = (short)f2bf(v0.w);
    w[4] = (short)f2bf(v1.x); w[5] = (short)f2bf(v1.y);
    w[6] = (short)f2bf(v1.z); w[7] = (short)f2bf(v1.w);
    *(s8v*)(Xs + (m << 7) + ((c ^ (m & 15)) << 3)) = w;
  }

  const f4v zero4 = {0.0f, 0.0f, 0.0f, 0.0f};
  f4v oacc[4][4];
#pragma unroll
  for (int i = 0; i < 4; ++i)
#pragma unroll
    for (int j = 0; j < 4; ++j) oacc[i][j] = zero4;

  const int w_h  = (wid >> 1) << 4;  // stage1: h-offset 0/16
  const int w_m1 = (wid & 1) << 6;   // stage1: m-offset 0/64
  const int w_m2 = (wid >> 1) << 6;  // stage2: m-offset 0/64
  const int w_o  = (wid & 1) << 6;   // stage2: o-offset 0/64

  for (int ch = 0; ch < 16; ++ch) {
    const int h0 = ch << 5;
    __syncthreads();   // prev chunk's stage2 done reading Hs/W2s; W1s free
    // ---- stage W1 chunk [32h][128d] (already bf16, contiguous copy) ----
#pragma unroll
    for (int it = 0; it < 2; ++it) {
      int s = (it << 8) + tid;            // 512 slots of 16B
      int r = s >> 4, c = s & 15;
      i4v v = *(const i4v*)(W1e + (size_t)(h0 + r) * DIN + (c << 3));
      *(i4v*)(W1s + (r << 7) + ((c ^ (r & 15)) << 3)) = v;
    }
    // ---- stage W2 chunk [128o][32h] ----
#pragma unroll
    for (int it = 0; it < 2; ++it) {
      int s = (it << 8) + tid;
      int r = s >> 2, c = s & 3;
      i4v v = *(const i4v*)(W2e + (size_t)r * DH + h0 + (c << 3));
      *(i4v*)(W2s + (r << 5) + ((c ^ ((r >> 1) & 3)) << 3)) = v;
    }
    __syncthreads();

    // ---- stage 1: Ht[32][128], this wave: h in [w_h,+16), m in [w_m1,+64) ----
    f4v hacc[4];
    hacc[0] = zero4; hacc[1] = zero4; hacc[2] = zero4; hacc[3] = zero4;
#pragma unroll
    for (int ks = 0; ks < 4; ++ks) {
      int hl = w_h + l16;
      int ca = (ks << 2) + quad;          // logical 16B chunk (k)
      s8v af = *(const s8v*)(W1s + (hl << 7) + ((ca ^ (hl & 15)) << 3));
#pragma unroll
      for (int mt = 0; mt < 4; ++mt) {
        int m = w_m1 + (mt << 4) + l16;
        s8v bf = *(const s8v*)(Xs + (m << 7) + ((ca ^ (m & 15)) << 3));
        hacc[mt] = __builtin_amdgcn_mfma_f32_16x16x32_bf16(af, bf, hacc[mt], 0, 0, 0);
      }
    }
    // ---- gelu + pack 4 consecutive h -> one b64 into Hs[m][h] ----
#pragma unroll
    for (int mt = 0; mt < 4; ++mt) {
      int m  = w_m1 + (mt << 4) + l16;
      int hq = w_h + (quad << 2);         // multiple of 4 in [0,32)
      ushort4 w;
      w.x = f2bf(gelu_f(hacc[mt][0]));
      w.y = f2bf(gelu_f(hacc[mt][1]));
      w.z = f2bf(gelu_f(hacc[mt][2]));
      w.w = f2bf(gelu_f(hacc[mt][3]));
      int cc = hq >> 3, half = (hq >> 2) & 1;
      *(ushort4*)(Hs + (m << 5) + ((cc ^ ((m >> 1) & 3)) << 3) + (half << 2)) = w;
    }
    __syncthreads();

    // ---- stage 2: out[m][o] += H[m][32] @ W2[32][o]  (K=32, 1 k-step) ----
    s8v af2[4], bf2[4];
#pragma unroll
    for (int mt = 0; mt < 4; ++mt) {
      int m = w_m2 + (mt << 4) + l16;
      af2[mt] = *(const s8v*)(Hs + (m << 5) + ((quad ^ ((m >> 1) & 3)) << 3));
    }
#pragma unroll
    for (int ot = 0; ot < 4; ++ot) {
      int o = w_o + (ot << 4) + l16;
      bf2[ot] = *(const s8v*)(W2s + (o << 5) + ((quad ^ ((o >> 1) & 3)) << 3));
    }
#pragma unroll
    for (int mt = 0; mt < 4; ++mt)
#pragma unroll
      for (int ot = 0; ot < 4; ++ot)
        oacc[mt][ot] = __builtin_amdgcn_mfma_f32_16x16x32_bf16(af2[mt], bf2[ot], oacc[mt][ot], 0, 0, 0);
  }

  // ---- epilogue: fp32 store (D layout: col=o=l16, rows = quad*4+r) ----
#pragma unroll
  for (int mt = 0; mt < 4; ++mt) {
    int mb = w_m2 + (mt << 4) + (quad << 2);
#pragma unroll
    for (int ot = 0; ot < 4; ++ot) {
      int o = w_o + (ot << 4) + l16;
      float* q = Oe + (size_t)mb * DOUT + o;
      q[0 * DOUT] = oacc[mt][ot][0];
      q[1 * DOUT] = oacc[mt][ot][1];
      q[2 * DOUT] = oacc[mt][ot][2];
      q[3 * DOUT] = oacc[mt][ot][3];
    }
  }
}

extern "C" void kernel_launch(void* const* d_in, const int* in_sizes, int n_in,
                              void* d_out, int out_size, void* d_ws, size_t ws_size,
                              hipStream_t stream) {
  const float* X  = (const float*)d_in[0];
  const float* W1 = (const float*)d_in[1];
  const float* W2 = (const float*)d_in[2];
  float* Out = (float*)d_out;

  ushort* W1t = (ushort*)d_ws;                                // [e][h][d] bf16, 16 MB
  ushort* W2t = (ushort*)d_ws + (size_t)NE * DH * DIN;        // [e][o][h] bf16, 16 MB

  transpose_cvt<<<NE * (DIN / 64) * (DH / 64), 256, 0, stream>>>(W1, W1t, DIN, DH);
  transpose_cvt<<<NE * (DH / 64) * (DOUT / 64), 256, 0, stream>>>(W2, W2t, DH, DOUT);
  moe_fused<<<NE * (NT / 128), 256, 0, stream>>>(X, W1t, W2t, Out);
}

// Round 3
// 336.914 us; speedup vs baseline: 1.1493x; 1.1493x over previous
//
#include <hip/hip_runtime.h>
#include <hip/hip_bf16.h>
#include <stdint.h>

typedef __attribute__((ext_vector_type(8))) short s8v;   // 8 bf16 = K32 MFMA A/B frag
typedef __attribute__((ext_vector_type(4))) short s4v;   // 4 bf16 = K16 MFMA A/B frag
typedef __attribute__((ext_vector_type(4))) float f4v;   // MFMA C/D frag

#define NE   128
#define NT   2048
#define DIN  128
#define DH   512
#define DOUT 128

#define MFMA32(a,b,c) __builtin_amdgcn_mfma_f32_16x16x32_bf16(a,b,c,0,0,0)
// gfx90a-era builtin, valid on gfx950 (v_mfma_f32_16x16x16_bf16, A/B = short4).
// NOTE: do NOT guard with __has_builtin — it returns false in the HOST pass
// and the fallback path is what broke round 2.
#define MFMA16(a,b,c) __builtin_amdgcn_mfma_f32_16x16x16bf16_1k(a,b,c,0,0,0)

// async global->LDS, 16B per lane; LDS dest must be wave-uniform base + lane*16
#define GLOAD16(g,l) __builtin_amdgcn_global_load_lds( \
    (const __attribute__((address_space(1))) void*)(g), \
    (__attribute__((address_space(3))) void*)(l), 16, 0, 0)

__device__ __forceinline__ __hip_bfloat162 pk2(float a, float b) {
  float2 t; t.x = a; t.y = b;
  return __float22bfloat162_rn(t);
}

__device__ __forceinline__ s8v pack8(float4 a, float4 b) {
  union { s8v v; __hip_bfloat162 h[4]; } u;
  u.h[0] = pk2(a.x, a.y); u.h[1] = pk2(a.z, a.w);
  u.h[2] = pk2(b.x, b.y); u.h[3] = pk2(b.z, b.w);
  return u.v;
}

// gelu(x) = x * sigmoid(x*(1.5957691 + 0.07135481*x^2))  (tanh-form rewritten)
__device__ __forceinline__ float gelu_f(float x) {
  float x2 = x * x;
  float p  = __builtin_fmaf(x2, 0.07135481f, 1.5957691f);
  float e  = __expf(-x * p);
  return x * __builtin_amdgcn_rcpf(1.0f + e);
}

// ---------------- prep: pack W1 (fp32 [e][128 d][512 h]) into K32 A-frag order
// W1F layout: [e][ht 0..31][ks 0..3][lane 0..63][8 bf16]; frag value j =
// W1[e][d = ks*32 + (lane>>4)*8 + j][h = ht*16 + (lane&15)]
__global__ __launch_bounds__(256) void pack_w1(const float* __restrict__ W1,
                                               ushort* __restrict__ W1F) {
  const int e = blockIdx.x >> 4, t2 = blockIdx.x & 15;   // t2 covers htiles 2*t2, 2*t2+1
  __shared__ float T[128][36];                            // [d][h-local 0..31]
  const int tid = threadIdx.x;
  const int d = tid >> 1, half = tid & 1;
  const float* src = W1 + (size_t)e * (DIN * DH) + (size_t)d * DH + t2 * 32 + half * 16;
  float4 v0 = *(const float4*)src;
  float4 v1 = *(const float4*)(src + 4);
  float4 v2 = *(const float4*)(src + 8);
  float4 v3 = *(const float4*)(src + 12);
  float* trow = &T[d][half * 16];
  *(float4*)(trow + 0) = v0; *(float4*)(trow + 4)  = v1;
  *(float4*)(trow + 8) = v2; *(float4*)(trow + 12) = v3;
  __syncthreads();
  const int lane = tid & 63, ks = tid >> 6;
  const int q = lane >> 4, l16 = lane & 15;
#pragma unroll
  for (int hl = 0; hl < 2; ++hl) {
    float g[8];
#pragma unroll
    for (int j = 0; j < 8; ++j) g[j] = T[ks * 32 + q * 8 + j][hl * 16 + l16];
    float4 a; a.x = g[0]; a.y = g[1]; a.z = g[2]; a.w = g[3];
    float4 b; b.x = g[4]; b.y = g[5]; b.z = g[6]; b.w = g[7];
    *(s8v*)(W1F + ((((size_t)e * 32 + t2 * 2 + hl) * 4) + ks) * 512 + lane * 8) = pack8(a, b);
  }
}

// ---------------- prep: pack W2 (fp32 [e][512 h][128 o]) into K16 B-frag order
// W2F layout: [e][ht 0..31][ot 0..7][lane 0..63][4 bf16]; frag value j =
// W2[e][h = ht*16 + (lane>>4)*4 + j][o = ot*16 + (lane&15)]
__global__ __launch_bounds__(256) void pack_w2(const float* __restrict__ W2,
                                               ushort* __restrict__ W2F) {
  const int e = blockIdx.x >> 5, ht = blockIdx.x & 31;
  __shared__ float T[16][132];                            // [h-local][o]
  const int tid = threadIdx.x;
  const int h = tid >> 4, c16 = tid & 15;
  const float* src = W2 + (size_t)e * (DH * DOUT) + (size_t)(ht * 16 + h) * DOUT + c16 * 8;
  float4 v0 = *(const float4*)src;
  float4 v1 = *(const float4*)(src + 4);
  float* trow = &T[h][c16 * 8];
  *(float4*)(trow + 0) = v0; *(float4*)(trow + 4) = v1;
  __syncthreads();
  const int lane = tid & 63;
  const int q = lane >> 4, l16 = lane & 15;
#pragma unroll
  for (int i = 0; i < 2; ++i) {
    int ot = (tid >> 6) + i * 4;
    float g0 = T[4 * q + 0][ot * 16 + l16];
    float g1 = T[4 * q + 1][ot * 16 + l16];
    float g2 = T[4 * q + 2][ot * 16 + l16];
    float g3 = T[4 * q + 3][ot * 16 + l16];
    union { s4v v; __hip_bfloat162 h2[2]; } u;
    u.h2[0] = pk2(g0, g1); u.h2[1] = pk2(g2, g3);
    *(s4v*)(W2F + (((size_t)e * 32 + ht) * 8 + ot) * 256 + lane * 4) = u.v;
  }
}

// ---------------- fused main kernel ----------------
// Block = 128 tokens of one expert, 4 waves; wave w owns m-range [32w, 32w+32).
// X frags live in VGPRs for the whole block (loaded once, fp32->bf16 in-reg).
// Stage1 (K=32): Ht = W1 . X^T  -> D regs ARE the K16 A-frag after gelu+pack.
// Stage2 (K=16): out += gelu(H) . W2, B-frags from frag-packed LDS (linear,
// conflict-free). Weights double-buffered via global_load_lds, 1 barrier/chunk.
__global__ __launch_bounds__(256, 3) void moe_fused(
    const float* __restrict__ X, const ushort* __restrict__ W1F,
    const ushort* __restrict__ W2F, float* __restrict__ Out) {
  __shared__ __align__(16) ushort W1s[2][4096];  // chunk: 2 htiles x 4 ks x 512
  __shared__ __align__(16) ushort W2s[2][4096];  // chunk: 2 htiles x 8 ot x 256

  const int tid  = threadIdx.x;
  const int lane = tid & 63;
  const int wid  = tid >> 6;
  const int q    = lane >> 4;
  const int l16  = lane & 15;

  const int e    = blockIdx.x >> 4;
  const int tile = blockIdx.x & 15;

  const float* Xe  = X + ((size_t)e * NT + (size_t)tile * 128) * DIN;
  const ushort* W1e = W1F + (size_t)e * 65536;
  const ushort* W2e = W2F + (size_t)e * 65536;
  float* Oe = Out + ((size_t)e * NT + (size_t)tile * 128) * DOUT;

  // ---- load this wave's X fragments into registers (once) ----
  s8v xf[2][4];
#pragma unroll
  for (int mt = 0; mt < 2; ++mt) {
#pragma unroll
    for (int ks = 0; ks < 4; ++ks) {
      const float* p = Xe + (size_t)(wid * 32 + mt * 16 + l16) * DIN + ks * 32 + q * 8;
      float4 v0 = *(const float4*)p;
      float4 v1 = *(const float4*)(p + 4);
      xf[mt][ks] = pack8(v0, v1);
    }
  }

  const f4v zero4 = {0.0f, 0.0f, 0.0f, 0.0f};
  f4v oacc[2][8];
#pragma unroll
  for (int mt = 0; mt < 2; ++mt)
#pragma unroll
    for (int ot = 0; ot < 8; ++ot) oacc[mt][ot] = zero4;

  // ---- stage chunk 0 into buf 0 ----
  {
    const ushort* g1 = W1e;
    const ushort* g2 = W2e;
#pragma unroll
    for (int i = 0; i < 2; ++i) {
      int u = i * 256 + tid;
      GLOAD16(g1 + u * 8, &W1s[0][u * 8]);
      GLOAD16(g2 + u * 8, &W2s[0][u * 8]);
    }
  }
  __syncthreads();

  for (int c = 0; c < 16; ++c) {
    const int buf = c & 1;
    if (c < 15) {               // prefetch next chunk into other buffer
      const ushort* g1 = W1e + (c + 1) * 4096;
      const ushort* g2 = W2e + (c + 1) * 4096;
#pragma unroll
      for (int i = 0; i < 2; ++i) {
        int u = i * 256 + tid;
        GLOAD16(g1 + u * 8, &W1s[buf ^ 1][u * 8]);
        GLOAD16(g2 + u * 8, &W2s[buf ^ 1][u * 8]);
      }
    }
#pragma unroll
    for (int hl = 0; hl < 2; ++hl) {
      // stage 1: K=32 over d, one 16-h tile
      f4v hacc[2]; hacc[0] = zero4; hacc[1] = zero4;
#pragma unroll
      for (int ks = 0; ks < 4; ++ks) {
        s8v af = *(const s8v*)&W1s[buf][(hl * 4 + ks) * 512 + lane * 8];
        hacc[0] = MFMA32(af, xf[0][ks], hacc[0]);
        hacc[1] = MFMA32(af, xf[1][ks], hacc[1]);
      }
      // gelu + pack: D regs (m=l16, h=4q+r) == K16 A-frag (row=l16, k=4q+j)
      s4v a2[2];
#pragma unroll
      for (int mt = 0; mt < 2; ++mt) {
        union { s4v v; __hip_bfloat162 h2[2]; } u;
        u.h2[0] = pk2(gelu_f(hacc[mt][0]), gelu_f(hacc[mt][1]));
        u.h2[1] = pk2(gelu_f(hacc[mt][2]), gelu_f(hacc[mt][3]));
        a2[mt] = u.v;
      }
      // stage 2: K=16, 8 o-tiles
#pragma unroll
      for (int ot = 0; ot < 8; ++ot) {
        s4v bf = *(const s4v*)&W2s[buf][(hl * 8 + ot) * 256 + lane * 4];
        oacc[0][ot] = MFMA16(a2[0], bf, oacc[0][ot]);
        oacc[1][ot] = MFMA16(a2[1], bf, oacc[1][ot]);
      }
    }
    __syncthreads();
  }

  // ---- epilogue: D layout col=o=l16, row m = 4q + r ----
#pragma unroll
  for (int mt = 0; mt < 2; ++mt) {
    const int mb = wid * 32 + mt * 16 + 4 * q;
#pragma unroll
    for (int ot = 0; ot < 8; ++ot) {
      float* p = Oe + (size_t)mb * DOUT + ot * 16 + l16;
      p[0 * DOUT] = oacc[mt][ot][0];
      p[1 * DOUT] = oacc[mt][ot][1];
      p[2 * DOUT] = oacc[mt][ot][2];
      p[3 * DOUT] = oacc[mt][ot][3];
    }
  }
}

extern "C" void kernel_launch(void* const* d_in, const int* in_sizes, int n_in,
                              void* d_out, int out_size, void* d_ws, size_t ws_size,
                              hipStream_t stream) {
  const float* X  = (const float*)d_in[0];
  const float* W1 = (const float*)d_in[1];
  const float* W2 = (const float*)d_in[2];
  float* Out = (float*)d_out;

  ushort* W1F = (ushort*)d_ws;                             // 128 KB/expert = 16.8 MB
  ushort* W2F = (ushort*)d_ws + (size_t)NE * 65536;        // 128 KB/expert = 16.8 MB

  pack_w1<<<NE * 16, 256, 0, stream>>>(W1, W1F);
  pack_w2<<<NE * 32, 256, 0, stream>>>(W2, W2F);
  moe_fused<<<NE * (NT / 128), 256, 0, stream>>>(X, W1F, W2F, Out);
}